// Round 9
// baseline (381.504 us; speedup 1.0000x reference)
//
#include <hip/hip_runtime.h>

#define DD 128

typedef __attribute__((ext_vector_type(8))) short short8;
typedef __attribute__((ext_vector_type(4))) float f32x4;
typedef __attribute__((ext_vector_type(4))) int i32x4;

__device__ __forceinline__ unsigned short f2bf(float f) {
    union { float f; unsigned int i; } c; c.f = f;
    unsigned int x = c.i;
    return (unsigned short)((x + 0x7fffu + ((x >> 16) & 1u)) >> 16);
}
__device__ __forceinline__ float bfu(unsigned short u) {
    union { unsigned int i; float f; } c; c.i = ((unsigned int)u) << 16; return c.f;
}
// Index accessor robust to int32 vs int64 (little-endian, nonneg values < 2^31)
__device__ __forceinline__ int idx_at(const int* p, int e, int is64) {
    return is64 ? p[2 * e] : p[e];
}
// Per-block int64 detection: int64 => odd 32-bit words (high halves) all zero.
__device__ __forceinline__ int block_is64(const int* dst, int nE, int* s_flag) {
    if (threadIdx.x == 0) *s_flag = 0;
    __syncthreads();
    int w = 2 * (int)threadIdx.x + 1;
    if (threadIdx.x < 128 && w < nE && dst[w] != 0) atomicOr(s_flag, 1);
    __syncthreads();
    return !*s_flag;
}

// ---- prep: one kernel, roles by blockIdx:
// [0, nConvH)      : h fp32 -> hB bf16 (2048 elems/block)
// [+nConvH)        : prevh fp32 -> bf16 into d_out slot second half (row*512+256)
// [+64)            : 3 weights transposed+converted into Wt; 4th = identity
// [+nDegB)         : zero deg
// [+nEmbB)         : emb fp32 -> embB bf16
__global__ __launch_bounds__(256) void prep_k(
    const float* __restrict__ h, const float* __restrict__ prevh,
    const float* __restrict__ W0, const float* __restrict__ W1,
    const float* __restrict__ W2, const float* __restrict__ emb,
    unsigned short* __restrict__ hB, char* __restrict__ aggP,
    unsigned short* __restrict__ embB, unsigned short* __restrict__ Wt,
    int* __restrict__ deg, int nN, int nEmbEl) {
    int tid = threadIdx.x;
    int bid = blockIdx.x;
    int totalH = nN * DD;
    int nConvH = (totalH + 2047) / 2048;
    if (bid < 2 * nConvH) {
        int which = bid >= nConvH;
        int base = (which ? bid - nConvH : bid) * 2048 + tid * 8;
        const float* S = which ? prevh : h;
        if (base + 8 <= totalH) {
            f32x4 x0 = *(const f32x4*)(S + base);
            f32x4 x1 = *(const f32x4*)(S + base + 4);
            short8 p;
            #pragma unroll
            for (int j = 0; j < 4; ++j) {
                p[j]     = (short)f2bf(x0[j]);
                p[4 + j] = (short)f2bf(x1[j]);
            }
            if (which) {
                int row = base >> 7, col = base & 127;
                *(short8*)(aggP + (size_t)row * 512 + 256 + col * 2) = p;
            } else {
                *(short8*)(hB + base) = p;
            }
        } else {
            for (int j = base; j < totalH; ++j) {
                unsigned short v = f2bf(S[j]);
                if (which) *(unsigned short*)(aggP + (size_t)(j >> 7) * 512 + 256 +
                                              (j & 127) * 2) = v;
                else hB[j] = v;
            }
        }
        return;
    }
    bid -= 2 * nConvH;
    if (bid < 64) {
        const float* Ws[3] = {W0, W1, W2};
        int w = bid >> 4, chunk = bid & 15;
        unsigned short* T = Wt + w * (DD * DD);
        #pragma unroll
        for (int i = 0; i < 4; ++i) {
            int t = chunk * 1024 + i * 256 + tid;
            int n = t >> 7, k = t & 127;
            T[t] = (w == 3) ? ((n == k) ? (unsigned short)0x3F80 : (unsigned short)0)
                            : f2bf(Ws[w][k * DD + n]);
        }
        return;
    }
    bid -= 64;
    int nDegB = (nN + 1023) / 1024;
    if (bid < nDegB) {
        int base = bid * 1024 + tid * 4;
        if (base + 4 <= nN) *(i32x4*)(deg + base) = (i32x4){0, 0, 0, 0};
        else for (int j = base; j < nN; ++j) deg[j] = 0;
        return;
    }
    bid -= nDegB;
    int base = bid * 2048 + tid * 8;
    if (base + 8 <= nEmbEl) {
        f32x4 x0 = *(const f32x4*)(emb + base);
        f32x4 x1 = *(const f32x4*)(emb + base + 4);
        short8 p;
        #pragma unroll
        for (int j = 0; j < 4; ++j) {
            p[j]     = (short)f2bf(x0[j]);
            p[4 + j] = (short)f2bf(x1[j]);
        }
        *(short8*)(embB + base) = p;
    } else {
        for (int j = base; j < nEmbEl; ++j) embB[j] = f2bf(emb[j]);
    }
}

// ---- in-degree histogram (inline dtype detect)
__global__ __launch_bounds__(256) void hist_k(const int* dst, int nE, int* deg) {
    __shared__ int s_flag;
    int is64 = block_is64(dst, nE, &s_flag);
    int e = blockIdx.x * 256 + threadIdx.x;
    if (e >= nE) return;
    atomicAdd(deg + idx_at(dst, e, is64), 1);
}

// ---- exclusive scan, step 1
__global__ __launch_bounds__(1024) void scan1_k(const int* deg, int* off, int* bsum,
                                                int nN) {
    __shared__ int s[1024];
    int t = threadIdx.x, i = blockIdx.x * 1024 + t;
    int v = (i < nN) ? deg[i] : 0;
    s[t] = v;
    __syncthreads();
    for (int d = 1; d < 1024; d <<= 1) {
        int x = (t >= d) ? s[t - d] : 0;
        __syncthreads();
        s[t] += x;
        __syncthreads();
    }
    if (i < nN) off[i] = s[t] - v;
    if (t == 1023) bsum[blockIdx.x] = s[1023];
}

// ---- steps 2+3 merged
__global__ __launch_bounds__(1024) void scan23_k(const int* bsum, int* off,
                                                 int* cursor, int nN, int nB) {
    __shared__ int s[1024];
    int t = threadIdx.x;
    s[t] = (t < nB) ? bsum[t] : 0;
    __syncthreads();
    for (int d = 1; d < 1024; d <<= 1) {
        int x = (t >= d) ? s[t - d] : 0;
        __syncthreads();
        s[t] += x;
        __syncthreads();
    }
    int base = (blockIdx.x == 0) ? 0 : s[blockIdx.x - 1];
    int i = blockIdx.x * 1024 + t;
    if (i < nN) {
        int o = off[i] + base;
        off[i] = o;
        cursor[i] = o;
    }
}

// ---- counting sort: packed edge word = src | (etype<<17); bucketed by dst
__global__ __launch_bounds__(256) void sort_k(const int* src, const int* dst,
                                              const int* et, int nE,
                                              int* cursor, unsigned int* edges) {
    __shared__ int s_flag;
    int is64 = block_is64(dst, nE, &s_flag);
    int e = blockIdx.x * 256 + threadIdx.x;
    if (e >= nE) return;
    int d = idx_at(dst, e, is64);
    int pos = atomicAdd(cursor + d, 1);
    edges[pos] = (unsigned int)idx_at(src, e, is64) |
                 ((unsigned int)idx_at(et, e, is64) << 17);
}

// ---- CSR gather, all-bf16: agg[v] = norm[v] * sum (hB[src]+embB[etype]);
// 16 lanes per edge (4 in flight); packed bf16 into first 256B of d_out slot.
__global__ __launch_bounds__(256) void gather_k(
    const unsigned short* __restrict__ hB, const unsigned short* __restrict__ embB,
    const unsigned int* __restrict__ edges, const int* __restrict__ off,
    const int* __restrict__ deg, const float* __restrict__ normv,
    char* __restrict__ aggP, int nN) {
    int lane = threadIdx.x & 63;
    int v = blockIdx.x * 4 + (threadIdx.x >> 6);
    if (v >= nN) return;
    int slot = lane >> 4, l16 = lane & 15;
    int b = off[v], n = deg[v];
    float a[8] = {0.f, 0.f, 0.f, 0.f, 0.f, 0.f, 0.f, 0.f};
    for (int i = 0; i < n; i += 4) {
        int my = i + slot;
        if (my < n) {
            unsigned int p = edges[b + my];
            int s = (int)(p & 0x1FFFFu), r = (int)(p >> 17);
            short8 hv = *(const short8*)(hB + (size_t)s * DD + l16 * 8);
            short8 rv = *(const short8*)(embB + (size_t)r * DD + l16 * 8);
            #pragma unroll
            for (int j = 0; j < 8; ++j)
                a[j] += bfu((unsigned short)hv[j]) + bfu((unsigned short)rv[j]);
        }
    }
    #pragma unroll
    for (int j = 0; j < 8; ++j) {
        a[j] += __shfl_xor(a[j], 16);
        a[j] += __shfl_xor(a[j], 32);
    }
    if (slot == 0) {
        float nm = normv[v];
        short8 p;
        #pragma unroll
        for (int j = 0; j < 8; ++j) p[j] = (short)f2bf(a[j] * nm);
        *(short8*)(aggP + (size_t)v * 512 + l16 * 16) = p;
    }
}

// ---- fused 4-GEMM + epilogue. Block = 4 waves, 32 nodes (small tile for
// occupancy: 48 AGPR + ~70 VGPR -> 4 waves/SIMD). Wave wv -> cols [32wv,32wv+32).
// accM = agg@Wn + h@Wl; accG = pB@Ws; accP = pB@I (pv in regs).
// agg/pB live in d_out's own 512B row slots (read pre-sync, overwritten after).
// deg==0 rows patched exactly by fix_k afterwards.
__global__ __launch_bounds__(256, 4) void fused_k(
    const unsigned short* __restrict__ hB, const float* __restrict__ bias,
    const char* aggP,                    // = d_out: [0,256)=agg bf16, [256,512)=prevh bf16
    const unsigned short* __restrict__ Wt,
    float* out, int nN) {
    const int lane = threadIdx.x & 63;
    const int wv = threadIdx.x >> 6;
    const int q = lane >> 4, cl = lane & 15;
    const int node_base = blockIdx.x * 32;
    const int ncb = wv * 32;

    f32x4 accM[2][2], accG[2][2], accP[2][2];
    #pragma unroll
    for (int mt = 0; mt < 2; ++mt)
        #pragma unroll
        for (int nt = 0; nt < 2; ++nt) {
            accM[mt][nt] = (f32x4){0.f, 0.f, 0.f, 0.f};
            accG[mt][nt] = (f32x4){0.f, 0.f, 0.f, 0.f};
            accP[mt][nt] = (f32x4){0.f, 0.f, 0.f, 0.f};
        }

    // pass 1: accM = agg@Wn + hB@Wl
    #pragma unroll
    for (int g = 0; g < 2; ++g) {
        const unsigned short* Wg = Wt + g * (DD * DD);
        #pragma unroll
        for (int ks = 0; ks < 4; ++ks) {
            short8 bfr[2];
            #pragma unroll
            for (int nt = 0; nt < 2; ++nt)
                bfr[nt] = *(const short8*)(Wg + (ncb + nt * 16 + cl) * DD +
                                           ks * 32 + q * 8);
            #pragma unroll
            for (int mt = 0; mt < 2; ++mt) {
                int row = node_base + mt * 16 + cl;
                if (row > nN - 1) row = nN - 1;
                short8 a = (g == 0)
                    ? *(const short8*)(aggP + (size_t)row * 512 + ks * 64 + q * 16)
                    : *(const short8*)(hB + (size_t)row * DD + ks * 32 + q * 8);
                #pragma unroll
                for (int nt = 0; nt < 2; ++nt)
                    accM[mt][nt] = __builtin_amdgcn_mfma_f32_16x16x32_bf16(
                        a, bfr[nt], accM[mt][nt], 0, 0, 0);
            }
        }
    }
    // pass 2: accG = pB@Ws, accP = pB@I (same A fragment feeds both)
    #pragma unroll
    for (int ks = 0; ks < 4; ++ks) {
        short8 bS[2], bI[2];
        #pragma unroll
        for (int nt = 0; nt < 2; ++nt) {
            int n = (ncb + nt * 16 + cl) * DD + ks * 32 + q * 8;
            bS[nt] = *(const short8*)(Wt + 2 * DD * DD + n);
            bI[nt] = *(const short8*)(Wt + 3 * DD * DD + n);
        }
        #pragma unroll
        for (int mt = 0; mt < 2; ++mt) {
            int row = node_base + mt * 16 + cl;
            if (row > nN - 1) row = nN - 1;
            short8 a = *(const short8*)(aggP + (size_t)row * 512 + 256 +
                                        ks * 64 + q * 16);
            #pragma unroll
            for (int nt = 0; nt < 2; ++nt) {
                accG[mt][nt] = __builtin_amdgcn_mfma_f32_16x16x32_bf16(
                    a, bS[nt], accG[mt][nt], 0, 0, 0);
                accP[mt][nt] = __builtin_amdgcn_mfma_f32_16x16x32_bf16(
                    a, bI[nt], accP[mt][nt], 0, 0, 0);
            }
        }
    }

    float b0 = bias[ncb + cl], b1 = bias[ncb + 16 + cl];

    __syncthreads();   // all slot reads (all waves) done before epilogue writes

    // C/D layout: col = lane&15, row = quad*4 + reg
    #pragma unroll
    for (int mt = 0; mt < 2; ++mt) {
        #pragma unroll
        for (int r = 0; r < 4; ++r) {
            int node = node_base + mt * 16 + q * 4 + r;
            if (node >= nN) continue;
            #pragma unroll
            for (int nt = 0; nt < 2; ++nt) {
                int col = ncb + nt * 16 + cl;
                float sg = 1.0f / (1.0f + __expf(-(accG[mt][nt][r] + (nt ? b1 : b0))));
                float o  = sg * accM[mt][nt][r] + (1.0f - sg) * accP[mt][nt][r];
                out[(size_t)node * DD + col] = (o > 0.f ? o : 0.f);
            }
        }
    }
}

// ---- patch deg==0 nodes exactly (fp32)
__global__ __launch_bounds__(256) void fix_k(
    const float* __restrict__ h, const float* __restrict__ prevh,
    const float* __restrict__ bias, const float* __restrict__ We,
    const float* __restrict__ Wsk, const int* __restrict__ deg,
    float* __restrict__ out, int nN, int chunk) {
    __shared__ int list[256];
    __shared__ int cnt;
    __shared__ float hrow[DD], prow[DD], res[2][DD];
    int tid = threadIdx.x;
    int base = blockIdx.x * chunk;
    for (int c = base; c < base + chunk && c < nN; c += 256) {
        if (tid == 0) cnt = 0;
        __syncthreads();
        int v = c + tid;
        if (v < nN && v < base + chunk && deg[v] == 0)
            list[atomicAdd(&cnt, 1)] = v;
        __syncthreads();
        int m = cnt;
        for (int i = 0; i < m; ++i) {
            int node = list[i];
            if (tid < DD) hrow[tid] = h[(size_t)node * DD + tid];
            else prow[tid - DD] = prevh[(size_t)node * DD + tid - DD];
            __syncthreads();
            int col = tid & (DD - 1);
            int half = tid >> 7;
            const float* W = half ? Wsk : We;
            const float* x = half ? prow : hrow;
            float s = 0.f;
            for (int k = 0; k < DD; ++k) s += x[k] * W[k * DD + col];
            res[half][col] = s;
            __syncthreads();
            if (tid < DD) {
                float sg = 1.0f / (1.0f + __expf(-(res[1][col] + bias[col])));
                float o  = sg * res[0][col] + (1.0f - sg) * prow[col];
                out[(size_t)node * DD + col] = (o > 0.f ? o : 0.f);
            }
            __syncthreads();
        }
        __syncthreads();
    }
}

extern "C" void kernel_launch(void* const* d_in, const int* in_sizes, int n_in,
                              void* d_out, int out_size, void* d_ws, size_t ws_size,
                              hipStream_t stream) {
    const float* h     = (const float*)d_in[0];
    const float* prevh = (const float*)d_in[1];
    const float* emb   = (const float*)d_in[2];
    const float* normv = (const float*)d_in[3];
    const float* Wn    = (const float*)d_in[4];
    const float* Wl    = (const float*)d_in[5];
    const float* We    = (const float*)d_in[6];
    const float* Wsk   = (const float*)d_in[7];
    const float* bias  = (const float*)d_in[8];
    const int* src   = (const int*)d_in[9];
    const int* dst   = (const int*)d_in[10];
    const int* etype = (const int*)d_in[11];

    int nN = in_sizes[3];       // norm is [N,1]
    int nE = in_sizes[9];
    int nEmbEl = in_sizes[2];   // NUM_RELS * 128

    // ws: Wt 128KB (Wn,Wl,Wsk,I) | embB | deg off cursor bsum | edges u32 | hB
    // => ~29.6 MB
    char* w = (char*)d_ws;
    size_t o = 0;
    unsigned short* Wt = (unsigned short*)(w + o);  o += 4 * DD * DD * 2;
    unsigned short* embB = (unsigned short*)(w + o); o += ((size_t)nEmbEl * 2 + 255) & ~(size_t)255;
    int* deg    = (int*)(w + o);  o += ((size_t)nN * 4 + 15) & ~(size_t)15;
    int* offA   = (int*)(w + o);  o += ((size_t)nN * 4 + 15) & ~(size_t)15;
    int* cursor = (int*)(w + o);  o += ((size_t)nN * 4 + 15) & ~(size_t)15;
    int* bsum   = (int*)(w + o);  o += 4096;
    unsigned int* edges = (unsigned int*)(w + o); o += ((size_t)nE * 4 + 15) & ~(size_t)15;
    unsigned short* hB = (unsigned short*)(w + o);

    int nConvH = (nN * DD + 2047) / 2048;
    int nDegB  = (nN + 1023) / 1024;
    int nEmbB  = (nEmbEl + 2047) / 2048;
    int nB = (nN + 1023) / 1024;

    prep_k<<<2 * nConvH + 64 + nDegB + nEmbB, 256, 0, stream>>>(
        h, prevh, Wn, Wl, Wsk, emb, hB, (char*)d_out, embB, Wt, deg, nN, nEmbEl);
    hist_k<<<(nE + 255) / 256, 256, 0, stream>>>(dst, nE, deg);
    scan1_k<<<nB, 1024, 0, stream>>>(deg, offA, bsum, nN);
    scan23_k<<<nB, 1024, 0, stream>>>(bsum, offA, cursor, nN, nB);
    sort_k<<<(nE + 255) / 256, 256, 0, stream>>>(src, dst, etype, nE, cursor, edges);
    gather_k<<<(nN + 3) / 4, 256, 0, stream>>>(hB, embB, edges, offA, deg, normv,
                                               (char*)d_out, nN);
    fused_k<<<(nN + 31) / 32, 256, 0, stream>>>(hB, bias, (const char*)d_out, Wt,
                                                (float*)d_out, nN);
    int fgrid = 256;
    int chunk = ((nN + fgrid * 256 - 1) / (fgrid * 256)) * 256;
    fix_k<<<fgrid, 256, 0, stream>>>(h, prevh, bias, We, Wsk, deg, (float*)d_out,
                                     nN, chunk);
    (void)ws_size; (void)n_in; (void)out_size;
}

// Round 10
// 357.427 us; speedup vs baseline: 1.0674x; 1.0674x over previous
//
#include <hip/hip_runtime.h>

#define DD 128

typedef __attribute__((ext_vector_type(8))) short short8;
typedef __attribute__((ext_vector_type(4))) float f32x4;
typedef __attribute__((ext_vector_type(4))) int i32x4;

__device__ __forceinline__ unsigned short f2bf(float f) {
    union { float f; unsigned int i; } c; c.f = f;
    unsigned int x = c.i;
    return (unsigned short)((x + 0x7fffu + ((x >> 16) & 1u)) >> 16);
}
__device__ __forceinline__ float bfu(unsigned short u) {
    union { unsigned int i; float f; } c; c.i = ((unsigned int)u) << 16; return c.f;
}
// Index accessor robust to int32 vs int64 (little-endian, nonneg values < 2^31)
__device__ __forceinline__ int idx_at(const int* p, int e, int is64) {
    return is64 ? p[2 * e] : p[e];
}
// Per-block int64 detection: int64 => odd 32-bit words (high halves) all zero.
__device__ __forceinline__ int block_is64(const int* dst, int nE, int* s_flag) {
    if (threadIdx.x == 0) *s_flag = 0;
    __syncthreads();
    int w = 2 * (int)threadIdx.x + 1;
    if (threadIdx.x < 128 && w < nE && dst[w] != 0) atomicOr(s_flag, 1);
    __syncthreads();
    return !*s_flag;
}

// ---- prep: one kernel, roles by blockIdx:
// [0, nConvH)      : h fp32 -> hB bf16 (2048 elems/block)
// [+nConvH)        : prevh fp32 -> bf16 into d_out slot second half (row*512+256)
// [+64)            : 3 weights transposed+converted into Wt; 4th = identity
// [+nEmbB)         : emb fp32 -> embB bf16
// [+nHistB)        : in-degree histogram (deg pre-zeroed by memsetAsync)
__global__ __launch_bounds__(256) void prep_k(
    const float* __restrict__ h, const float* __restrict__ prevh,
    const float* __restrict__ W0, const float* __restrict__ W1,
    const float* __restrict__ W2, const float* __restrict__ emb,
    const int* __restrict__ dst,
    unsigned short* __restrict__ hB, char* __restrict__ aggP,
    unsigned short* __restrict__ embB, unsigned short* __restrict__ Wt,
    int* __restrict__ deg, int nN, int nEmbEl, int nE) {
    int tid = threadIdx.x;
    int bid = blockIdx.x;
    int totalH = nN * DD;
    int nConvH = (totalH + 2047) / 2048;
    if (bid < 2 * nConvH) {
        int which = bid >= nConvH;
        int base = (which ? bid - nConvH : bid) * 2048 + tid * 8;
        const float* S = which ? prevh : h;
        if (base + 8 <= totalH) {
            f32x4 x0 = *(const f32x4*)(S + base);
            f32x4 x1 = *(const f32x4*)(S + base + 4);
            short8 p;
            #pragma unroll
            for (int j = 0; j < 4; ++j) {
                p[j]     = (short)f2bf(x0[j]);
                p[4 + j] = (short)f2bf(x1[j]);
            }
            if (which) {
                int row = base >> 7, col = base & 127;
                *(short8*)(aggP + (size_t)row * 512 + 256 + col * 2) = p;
            } else {
                *(short8*)(hB + base) = p;
            }
        } else {
            for (int j = base; j < totalH; ++j) {
                unsigned short v = f2bf(S[j]);
                if (which) *(unsigned short*)(aggP + (size_t)(j >> 7) * 512 + 256 +
                                              (j & 127) * 2) = v;
                else hB[j] = v;
            }
        }
        return;
    }
    bid -= 2 * nConvH;
    if (bid < 64) {
        const float* Ws[3] = {W0, W1, W2};
        int w = bid >> 4, chunk = bid & 15;
        unsigned short* T = Wt + w * (DD * DD);
        #pragma unroll
        for (int i = 0; i < 4; ++i) {
            int t = chunk * 1024 + i * 256 + tid;
            int n = t >> 7, k = t & 127;
            T[t] = (w == 3) ? ((n == k) ? (unsigned short)0x3F80 : (unsigned short)0)
                            : f2bf(Ws[w][k * DD + n]);
        }
        return;
    }
    bid -= 64;
    int nEmbB = (nEmbEl + 2047) / 2048;
    if (bid < nEmbB) {
        int base = bid * 2048 + tid * 8;
        if (base + 8 <= nEmbEl) {
            f32x4 x0 = *(const f32x4*)(emb + base);
            f32x4 x1 = *(const f32x4*)(emb + base + 4);
            short8 p;
            #pragma unroll
            for (int j = 0; j < 4; ++j) {
                p[j]     = (short)f2bf(x0[j]);
                p[4 + j] = (short)f2bf(x1[j]);
            }
            *(short8*)(embB + base) = p;
        } else {
            for (int j = base; j < nEmbEl; ++j) embB[j] = f2bf(emb[j]);
        }
        return;
    }
    bid -= nEmbB;
    // histogram role
    __shared__ int s_flag;
    int is64 = block_is64(dst, nE, &s_flag);
    int e = bid * 256 + tid;
    if (e < nE) atomicAdd(deg + idx_at(dst, e, is64), 1);
}

// ---- exclusive scan, step 1
__global__ __launch_bounds__(1024) void scan1_k(const int* deg, int* off, int* bsum,
                                                int nN) {
    __shared__ int s[1024];
    int t = threadIdx.x, i = blockIdx.x * 1024 + t;
    int v = (i < nN) ? deg[i] : 0;
    s[t] = v;
    __syncthreads();
    for (int d = 1; d < 1024; d <<= 1) {
        int x = (t >= d) ? s[t - d] : 0;
        __syncthreads();
        s[t] += x;
        __syncthreads();
    }
    if (i < nN) off[i] = s[t] - v;
    if (t == 1023) bsum[blockIdx.x] = s[1023];
}

// ---- steps 2+3 merged
__global__ __launch_bounds__(1024) void scan23_k(const int* bsum, int* off,
                                                 int* cursor, int nN, int nB) {
    __shared__ int s[1024];
    int t = threadIdx.x;
    s[t] = (t < nB) ? bsum[t] : 0;
    __syncthreads();
    for (int d = 1; d < 1024; d <<= 1) {
        int x = (t >= d) ? s[t - d] : 0;
        __syncthreads();
        s[t] += x;
        __syncthreads();
    }
    int base = (blockIdx.x == 0) ? 0 : s[blockIdx.x - 1];
    int i = blockIdx.x * 1024 + t;
    if (i < nN) {
        int o = off[i] + base;
        off[i] = o;
        cursor[i] = o;
    }
}

// ---- counting sort: packed edge word = src | (etype<<17); bucketed by dst
__global__ __launch_bounds__(256) void sort_k(const int* src, const int* dst,
                                              const int* et, int nE,
                                              int* cursor, unsigned int* edges) {
    __shared__ int s_flag;
    int is64 = block_is64(dst, nE, &s_flag);
    int e = blockIdx.x * 256 + threadIdx.x;
    if (e >= nE) return;
    int d = idx_at(dst, e, is64);
    int pos = atomicAdd(cursor + d, 1);
    edges[pos] = (unsigned int)idx_at(src, e, is64) |
                 ((unsigned int)idx_at(et, e, is64) << 17);
}

// ---- CSR gather, all-bf16: agg[v] = norm[v] * sum (hB[src]+embB[etype]);
// 16 lanes per edge; 8 edges per iteration (two 4-edge rounds, loads issued
// before accumulation for MLP). Packed bf16 into first 256B of d_out slot.
__global__ __launch_bounds__(256) void gather_k(
    const unsigned short* __restrict__ hB, const unsigned short* __restrict__ embB,
    const unsigned int* __restrict__ edges, const int* __restrict__ off,
    const int* __restrict__ deg, const float* __restrict__ normv,
    char* __restrict__ aggP, int nN) {
    int lane = threadIdx.x & 63;
    int v = blockIdx.x * 4 + (threadIdx.x >> 6);
    if (v >= nN) return;
    int slot = lane >> 4, l16 = lane & 15;
    int b = off[v], n = deg[v];
    float a[8] = {0.f, 0.f, 0.f, 0.f, 0.f, 0.f, 0.f, 0.f};
    for (int base = 0; base < n; base += 8) {
        int m0 = base + slot, m1 = base + 4 + slot;
        bool v0 = m0 < n, v1 = m1 < n;
        unsigned int w0 = 0, w1 = 0;
        if (v0) w0 = edges[b + m0];
        if (v1) w1 = edges[b + m1];
        short8 hv0, rv0, hv1, rv1;
        if (v0) {
            hv0 = *(const short8*)(hB + (size_t)(w0 & 0x1FFFFu) * DD + l16 * 8);
            rv0 = *(const short8*)(embB + (size_t)(w0 >> 17) * DD + l16 * 8);
        }
        if (v1) {
            hv1 = *(const short8*)(hB + (size_t)(w1 & 0x1FFFFu) * DD + l16 * 8);
            rv1 = *(const short8*)(embB + (size_t)(w1 >> 17) * DD + l16 * 8);
        }
        if (v0) {
            #pragma unroll
            for (int j = 0; j < 8; ++j)
                a[j] += bfu((unsigned short)hv0[j]) + bfu((unsigned short)rv0[j]);
        }
        if (v1) {
            #pragma unroll
            for (int j = 0; j < 8; ++j)
                a[j] += bfu((unsigned short)hv1[j]) + bfu((unsigned short)rv1[j]);
        }
    }
    #pragma unroll
    for (int j = 0; j < 8; ++j) {
        a[j] += __shfl_xor(a[j], 16);
        a[j] += __shfl_xor(a[j], 32);
    }
    if (slot == 0) {
        float nm = normv[v];
        short8 p;
        #pragma unroll
        for (int j = 0; j < 8; ++j) p[j] = (short)f2bf(a[j] * nm);
        *(short8*)(aggP + (size_t)v * 512 + l16 * 16) = p;
    }
}

// ---- fused 4-GEMM + epilogue (round-8 config: 64-node tile, fat registers).
// Block = 4 waves, wave wv -> cols [32wv,32wv+32). accM = agg@Wn + h@Wl;
// accG = pB@Ws; accP = pB@I. Slots in d_out (read pre-sync, overwritten after).
// deg==0 rows patched exactly by fix_k afterwards.
__global__ __launch_bounds__(256, 2) void fused_k(
    const unsigned short* __restrict__ hB, const float* __restrict__ bias,
    const char* aggP,                    // = d_out: [0,256)=agg bf16, [256,512)=prevh bf16
    const unsigned short* __restrict__ Wt,
    float* out, int nN) {
    const int lane = threadIdx.x & 63;
    const int wv = threadIdx.x >> 6;
    const int q = lane >> 4, cl = lane & 15;
    const int node_base = blockIdx.x * 64;
    const int ncb = wv * 32;

    f32x4 accM[4][2], accG[4][2], accP[4][2];
    #pragma unroll
    for (int mt = 0; mt < 4; ++mt)
        #pragma unroll
        for (int nt = 0; nt < 2; ++nt) {
            accM[mt][nt] = (f32x4){0.f, 0.f, 0.f, 0.f};
            accG[mt][nt] = (f32x4){0.f, 0.f, 0.f, 0.f};
            accP[mt][nt] = (f32x4){0.f, 0.f, 0.f, 0.f};
        }

    // pass 1: accM = agg@Wn + hB@Wl
    #pragma unroll
    for (int g = 0; g < 2; ++g) {
        const unsigned short* Wg = Wt + g * (DD * DD);
        #pragma unroll
        for (int ks = 0; ks < 4; ++ks) {
            short8 bfr[2];
            #pragma unroll
            for (int nt = 0; nt < 2; ++nt)
                bfr[nt] = *(const short8*)(Wg + (ncb + nt * 16 + cl) * DD +
                                           ks * 32 + q * 8);
            #pragma unroll
            for (int mt = 0; mt < 4; ++mt) {
                int row = node_base + mt * 16 + cl;
                if (row > nN - 1) row = nN - 1;
                short8 a = (g == 0)
                    ? *(const short8*)(aggP + (size_t)row * 512 + ks * 64 + q * 16)
                    : *(const short8*)(hB + (size_t)row * DD + ks * 32 + q * 8);
                #pragma unroll
                for (int nt = 0; nt < 2; ++nt)
                    accM[mt][nt] = __builtin_amdgcn_mfma_f32_16x16x32_bf16(
                        a, bfr[nt], accM[mt][nt], 0, 0, 0);
            }
        }
    }
    // pass 2: accG = pB@Ws, accP = pB@I (same A fragment feeds both)
    #pragma unroll
    for (int ks = 0; ks < 4; ++ks) {
        short8 bS[2], bI[2];
        #pragma unroll
        for (int nt = 0; nt < 2; ++nt) {
            int n = (ncb + nt * 16 + cl) * DD + ks * 32 + q * 8;
            bS[nt] = *(const short8*)(Wt + 2 * DD * DD + n);
            bI[nt] = *(const short8*)(Wt + 3 * DD * DD + n);
        }
        #pragma unroll
        for (int mt = 0; mt < 4; ++mt) {
            int row = node_base + mt * 16 + cl;
            if (row > nN - 1) row = nN - 1;
            short8 a = *(const short8*)(aggP + (size_t)row * 512 + 256 +
                                        ks * 64 + q * 16);
            #pragma unroll
            for (int nt = 0; nt < 2; ++nt) {
                accG[mt][nt] = __builtin_amdgcn_mfma_f32_16x16x32_bf16(
                    a, bS[nt], accG[mt][nt], 0, 0, 0);
                accP[mt][nt] = __builtin_amdgcn_mfma_f32_16x16x32_bf16(
                    a, bI[nt], accP[mt][nt], 0, 0, 0);
            }
        }
    }

    float b0 = bias[ncb + cl], b1 = bias[ncb + 16 + cl];

    __syncthreads();   // all slot reads (all waves) done before epilogue writes

    // C/D layout: col = lane&15, row = quad*4 + reg
    #pragma unroll
    for (int mt = 0; mt < 4; ++mt) {
        #pragma unroll
        for (int r = 0; r < 4; ++r) {
            int node = node_base + mt * 16 + q * 4 + r;
            if (node >= nN) continue;
            #pragma unroll
            for (int nt = 0; nt < 2; ++nt) {
                int col = ncb + nt * 16 + cl;
                float sg = 1.0f / (1.0f + __expf(-(accG[mt][nt][r] + (nt ? b1 : b0))));
                float o  = sg * accM[mt][nt][r] + (1.0f - sg) * accP[mt][nt][r];
                out[(size_t)node * DD + col] = (o > 0.f ? o : 0.f);
            }
        }
    }
}

// ---- patch deg==0 nodes exactly (fp32)
__global__ __launch_bounds__(256) void fix_k(
    const float* __restrict__ h, const float* __restrict__ prevh,
    const float* __restrict__ bias, const float* __restrict__ We,
    const float* __restrict__ Wsk, const int* __restrict__ deg,
    float* __restrict__ out, int nN, int chunk) {
    __shared__ int list[256];
    __shared__ int cnt;
    __shared__ float hrow[DD], prow[DD], res[2][DD];
    int tid = threadIdx.x;
    int base = blockIdx.x * chunk;
    for (int c = base; c < base + chunk && c < nN; c += 256) {
        if (tid == 0) cnt = 0;
        __syncthreads();
        int v = c + tid;
        if (v < nN && v < base + chunk && deg[v] == 0)
            list[atomicAdd(&cnt, 1)] = v;
        __syncthreads();
        int m = cnt;
        for (int i = 0; i < m; ++i) {
            int node = list[i];
            if (tid < DD) hrow[tid] = h[(size_t)node * DD + tid];
            else prow[tid - DD] = prevh[(size_t)node * DD + tid - DD];
            __syncthreads();
            int col = tid & (DD - 1);
            int half = tid >> 7;
            const float* W = half ? Wsk : We;
            const float* x = half ? prow : hrow;
            float s = 0.f;
            for (int k = 0; k < DD; ++k) s += x[k] * W[k * DD + col];
            res[half][col] = s;
            __syncthreads();
            if (tid < DD) {
                float sg = 1.0f / (1.0f + __expf(-(res[1][col] + bias[col])));
                float o  = sg * res[0][col] + (1.0f - sg) * prow[col];
                out[(size_t)node * DD + col] = (o > 0.f ? o : 0.f);
            }
            __syncthreads();
        }
        __syncthreads();
    }
}

extern "C" void kernel_launch(void* const* d_in, const int* in_sizes, int n_in,
                              void* d_out, int out_size, void* d_ws, size_t ws_size,
                              hipStream_t stream) {
    const float* h     = (const float*)d_in[0];
    const float* prevh = (const float*)d_in[1];
    const float* emb   = (const float*)d_in[2];
    const float* normv = (const float*)d_in[3];
    const float* Wn    = (const float*)d_in[4];
    const float* Wl    = (const float*)d_in[5];
    const float* We    = (const float*)d_in[6];
    const float* Wsk   = (const float*)d_in[7];
    const float* bias  = (const float*)d_in[8];
    const int* src   = (const int*)d_in[9];
    const int* dst   = (const int*)d_in[10];
    const int* etype = (const int*)d_in[11];

    int nN = in_sizes[3];       // norm is [N,1]
    int nE = in_sizes[9];
    int nEmbEl = in_sizes[2];   // NUM_RELS * 128

    // ws: Wt 128KB (Wn,Wl,Wsk,I) | embB | deg off cursor bsum | edges u32 | hB
    // => ~29.6 MB
    char* w = (char*)d_ws;
    size_t o = 0;
    unsigned short* Wt = (unsigned short*)(w + o);  o += 4 * DD * DD * 2;
    unsigned short* embB = (unsigned short*)(w + o); o += ((size_t)nEmbEl * 2 + 255) & ~(size_t)255;
    int* deg    = (int*)(w + o);  o += ((size_t)nN * 4 + 15) & ~(size_t)15;
    int* offA   = (int*)(w + o);  o += ((size_t)nN * 4 + 15) & ~(size_t)15;
    int* cursor = (int*)(w + o);  o += ((size_t)nN * 4 + 15) & ~(size_t)15;
    int* bsum   = (int*)(w + o);  o += 4096;
    unsigned int* edges = (unsigned int*)(w + o); o += ((size_t)nE * 4 + 15) & ~(size_t)15;
    unsigned short* hB = (unsigned short*)(w + o);

    int nConvH = (nN * DD + 2047) / 2048;
    int nEmbB  = (nEmbEl + 2047) / 2048;
    int nHistB = (nE + 255) / 256;
    int nB = (nN + 1023) / 1024;

    hipMemsetAsync(deg, 0, (size_t)nN * sizeof(int), stream);
    prep_k<<<2 * nConvH + 64 + nEmbB + nHistB, 256, 0, stream>>>(
        h, prevh, Wn, Wl, Wsk, emb, dst, hB, (char*)d_out, embB, Wt, deg,
        nN, nEmbEl, nE);
    scan1_k<<<nB, 1024, 0, stream>>>(deg, offA, bsum, nN);
    scan23_k<<<nB, 1024, 0, stream>>>(bsum, offA, cursor, nN, nB);
    sort_k<<<(nE + 255) / 256, 256, 0, stream>>>(src, dst, etype, nE, cursor, edges);
    gather_k<<<(nN + 3) / 4, 256, 0, stream>>>(hB, embB, edges, offA, deg, normv,
                                               (char*)d_out, nN);
    fused_k<<<(nN + 63) / 64, 256, 0, stream>>>(hB, bias, (const char*)d_out, Wt,
                                                (float*)d_out, nN);
    int fgrid = 256;
    int chunk = ((nN + fgrid * 256 - 1) / (fgrid * 256)) * 256;
    fix_k<<<fgrid, 256, 0, stream>>>(h, prevh, bias, We, Wsk, deg, (float*)d_out,
                                     nN, chunk);
    (void)ws_size; (void)n_in; (void)out_size;
}